// Round 1
// 571.510 us; speedup vs baseline: 1.0321x; 1.0321x over previous
//
#include <hip/hip_runtime.h>

#define NUM_HEAD 8
#define D_MODEL  512
#define HEAD_DIM 64
#define NSEQ     2048
// 0.125 * log2(e)
#define SCALE_LOG2E 0.18033688011112042f

typedef __attribute__((ext_vector_type(8))) short bf16x8;
typedef __attribute__((ext_vector_type(4))) float f32x4;

static __device__ __forceinline__ unsigned short f2bf(float f) {
    unsigned u = __builtin_bit_cast(unsigned, f);
    u += 0x7fffu + ((u >> 16) & 1u);   // RNE
    return (unsigned short)(u >> 16);
}
static __device__ __forceinline__ float bf2f(unsigned short h) {
    unsigned u = ((unsigned)h) << 16;
    return __builtin_bit_cast(float, u);
}
static __device__ __forceinline__ unsigned pk2(float a, float b) {
    return (unsigned)f2bf(a) | ((unsigned)f2bf(b) << 16);
}

// ---------------------------------------------------------------------------
// Projection: out = X @ W^T + bias, bf16.
//   z=0 (Q), z=1 (K): layout [b, h, n, 64]
//   z=2 (V):          layout [b, h, 64, n]  (pre-transposed for attn B-frags)
// Tile 128(M) x 64(N) x 32(K); 4 waves as 2x2, each wave 64x32 (4x2 mfma frags)
// Single launch, grid.z = 3  -> 3 blocks/CU instead of 1.
// ---------------------------------------------------------------------------
#define PSTR 40  // LDS row stride in bf16 elements (32 + 8 pad)

__global__ __launch_bounds__(256) void proj_kernel(
    const float* __restrict__ Xq, const float* __restrict__ Xk, const float* __restrict__ Xv,
    const float* __restrict__ Wq, const float* __restrict__ Wk, const float* __restrict__ Wv,
    const float* __restrict__ Bq, const float* __restrict__ Bk, const float* __restrict__ Bv,
    unsigned short* __restrict__ Oq, unsigned short* __restrict__ Ok,
    unsigned short* __restrict__ Ov)
{
    __shared__ unsigned short lA[128 * PSTR];
    __shared__ unsigned short lB[64 * PSTR];

    const int z = blockIdx.z;
    const float* X    = (z == 0) ? Xq : (z == 1) ? Xk : Xv;
    const float* W    = (z == 0) ? Wq : (z == 1) ? Wk : Wv;
    const float* bias = (z == 0) ? Bq : (z == 1) ? Bk : Bv;
    unsigned short* outp = (z == 0) ? Oq : (z == 1) ? Ok : Ov;

    const int tid  = threadIdx.x;
    const int lane = tid & 63, wid = tid >> 6;
    const int quad = lane >> 4, l15 = lane & 15;
    const int wm = (wid >> 1) * 64;   // wave m offset in tile
    const int wn = (wid & 1) * 32;    // wave n offset in tile
    const int m0 = blockIdx.x * 128, n0 = blockIdx.y * 64;

    f32x4 acc[4][2];
    const f32x4 zf = {0.f, 0.f, 0.f, 0.f};
#pragma unroll
    for (int mi = 0; mi < 4; mi++)
#pragma unroll
        for (int ni = 0; ni < 2; ni++) acc[mi][ni] = zf;

    const int arow = tid >> 1, akc = (tid & 1) * 16;  // A: 128 rows x 32k
    const int brow = tid >> 2, bkc = (tid & 3) * 8;   // B:  64 rows x 32k

    for (int k0 = 0; k0 < D_MODEL; k0 += 32) {
        const float* ap = X + (m0 + arow) * D_MODEL + k0 + akc;
        float4 a0 = *(const float4*)(ap);
        float4 a1 = *(const float4*)(ap + 4);
        float4 a2 = *(const float4*)(ap + 8);
        float4 a3 = *(const float4*)(ap + 12);
        uint4 w0, w1;
        w0.x = pk2(a0.x, a0.y); w0.y = pk2(a0.z, a0.w);
        w0.z = pk2(a1.x, a1.y); w0.w = pk2(a1.z, a1.w);
        w1.x = pk2(a2.x, a2.y); w1.y = pk2(a2.z, a2.w);
        w1.z = pk2(a3.x, a3.y); w1.w = pk2(a3.z, a3.w);
        *(uint4*)&lA[arow * PSTR + akc]     = w0;
        *(uint4*)&lA[arow * PSTR + akc + 8] = w1;
        const float* bp = W + (n0 + brow) * D_MODEL + k0 + bkc;
        float4 b0 = *(const float4*)(bp);
        float4 b1 = *(const float4*)(bp + 4);
        uint4 wb;
        wb.x = pk2(b0.x, b0.y); wb.y = pk2(b0.z, b0.w);
        wb.z = pk2(b1.x, b1.y); wb.w = pk2(b1.z, b1.w);
        *(uint4*)&lB[brow * PSTR + bkc] = wb;
        __syncthreads();

        bf16x8 aF[4], bF[2];
#pragma unroll
        for (int mi = 0; mi < 4; mi++)
            aF[mi] = *(const bf16x8*)&lA[(wm + mi * 16 + l15) * PSTR + quad * 8];
#pragma unroll
        for (int ni = 0; ni < 2; ni++)
            bF[ni] = *(const bf16x8*)&lB[(wn + ni * 16 + l15) * PSTR + quad * 8];
#pragma unroll
        for (int mi = 0; mi < 4; mi++)
#pragma unroll
            for (int ni = 0; ni < 2; ni++)
                acc[mi][ni] = __builtin_amdgcn_mfma_f32_16x16x32_bf16(
                    aF[mi], bF[ni], acc[mi][ni], 0, 0, 0);
        __syncthreads();
    }

    const float bv0 = bias[n0 + wn + l15];
    const float bv1 = bias[n0 + wn + 16 + l15];

    if (z == 2) {
        // V^T epilogue: out[bh][d][n]; 4 consecutive n per lane -> 8B store
#pragma unroll
        for (int mi = 0; mi < 4; mi++) {
            const int mbase = m0 + wm + mi * 16 + quad * 4;
            const int bb = mbase >> 11, n = mbase & 2047;
#pragma unroll
            for (int ni = 0; ni < 2; ni++) {
                const int c = n0 + wn + ni * 16 + l15;
                const int h = c >> 6, d = c & 63;
                const float badd = ni ? bv1 : bv0;
                ushort4 pk;
                pk.x = f2bf(acc[mi][ni][0] + badd);
                pk.y = f2bf(acc[mi][ni][1] + badd);
                pk.z = f2bf(acc[mi][ni][2] + badd);
                pk.w = f2bf(acc[mi][ni][3] + badd);
                *(ushort4*)&outp[((size_t)((bb * NUM_HEAD + h) * HEAD_DIM + d)) * NSEQ + n] = pk;
            }
        }
    } else {
#pragma unroll
        for (int mi = 0; mi < 4; mi++) {
            const int mbase = m0 + wm + mi * 16 + quad * 4;
#pragma unroll
            for (int ni = 0; ni < 2; ni++) {
                const int c = n0 + wn + ni * 16 + l15;
                const int h = c >> 6, d = c & 63;
                const float badd = ni ? bv1 : bv0;
#pragma unroll
                for (int r = 0; r < 4; r++) {
                    const int mm = mbase + r;
                    const int bb = mm >> 11, n = mm & 2047;
                    outp[((bb * NUM_HEAD + h) * NSEQ + n) * HEAD_DIM + d] =
                        f2bf(acc[mi][ni][r] + badd);
                }
            }
        }
    }
}

// ---------------------------------------------------------------------------
// Extract diagonal of pearson_matrix: diag[bh, k] = pearson[bh, k, k]
// ---------------------------------------------------------------------------
__global__ void diag_kernel(const float* __restrict__ pearson,
                            float* __restrict__ diag)
{
    const int t = blockIdx.x * blockDim.x + threadIdx.x;  // 32768 total
    const int bh = t >> 11, kk = t & 2047;
    diag[t] = pearson[((size_t)(bh * NSEQ + kk)) * NSEQ + kk];
}

// ---------------------------------------------------------------------------
// Fused flash-style attention — barrier-free.
//   S = Q K^T * scale; p = exp(S) (no max subtraction: |S| <~ 2)
//   l += rowsum(p); O += (p * mask * diag) @ V; out = O / l
// Each wave owns 16 q-rows independently (wave-private P strip in LDS).
// mask+K+diag register double-buffered (ping-pong, 2x-unrolled k loop);
// V B-frags load straight from global V^T (L2/L3-resident), issued at
// compute-top so their latency hides under the exp/P phase.
// ---------------------------------------------------------------------------
#define VSTR 72  // LDS row stride (64 + 8 pad) in bf16 elements

struct TileRegs {
    bf16x8 kF[4][2];
    float  mv[4][4];
    float  dg[4];
};

__global__ __launch_bounds__(256) void attn_kernel(
    const unsigned short* __restrict__ Qp, const unsigned short* __restrict__ Kp,
    const unsigned short* __restrict__ Vt, const float* __restrict__ diag,
    const float* __restrict__ mask, float* __restrict__ out)
{
    __shared__ unsigned short lP[4][16 * VSTR];   // per-wave 16q x 64k strip

    const int tid  = threadIdx.x;
    const int lane = tid & 63, wid = tid >> 6;
    const int quad = lane >> 4, l15 = lane & 15;
    const int bh = blockIdx.y;                    // b*8 + h
    const int q0 = blockIdx.x * 64 + wid * 16;    // this wave's q-strip

    const unsigned short* Qb = Qp + (size_t)bh * NSEQ * HEAD_DIM;
    const unsigned short* Kb = Kp + (size_t)bh * NSEQ * HEAD_DIM;
    const unsigned short* Vb = Vt + (size_t)bh * HEAD_DIM * NSEQ;
    const float* diagb = diag + bh * NSEQ;
    const float* mrow  = mask + (size_t)bh * NSEQ * NSEQ + (size_t)(q0 + quad * 4) * NSEQ;

    // Q fragments (persistent)
    bf16x8 qF[2];
    {
        const unsigned short* qp = Qb + (q0 + l15) * HEAD_DIM + quad * 8;
        qF[0] = *(const bf16x8*)qp;
        qF[1] = *(const bf16x8*)(qp + 32);
    }

    const f32x4 zf = {0.f, 0.f, 0.f, 0.f};
    f32x4 oacc[4] = {zf, zf, zf, zf};
    float lacc[4] = {0.f, 0.f, 0.f, 0.f};

    unsigned short* lPw = &lP[wid][0];

    auto load_tile = [&](TileRegs& t, int ktt) {
#pragma unroll
        for (int nt = 0; nt < 4; nt++) {
            const unsigned short* kp = Kb + (ktt + nt * 16 + l15) * HEAD_DIM + quad * 8;
            t.kF[nt][0] = *(const bf16x8*)kp;
            t.kF[nt][1] = *(const bf16x8*)(kp + 32);
        }
#pragma unroll
        for (int cf = 0; cf < 4; cf++) {
            t.dg[cf] = diagb[ktt + cf * 16 + l15];
#pragma unroll
            for (int r = 0; r < 4; r++)
                t.mv[cf][r] = mrow[(size_t)r * NSEQ + ktt + cf * 16 + l15];
        }
    };

    auto compute_tile = [&](const TileRegs& t, int ktt) {
        // V B-frags direct from global V^T (issued early, used after exp phase)
        bf16x8 vF[4][2];
#pragma unroll
        for (int nt = 0; nt < 4; nt++) {
            const unsigned short* vp = Vb + (nt * 16 + l15) * NSEQ + ktt + quad * 8;
            vF[nt][0] = *(const bf16x8*)vp;
            vF[nt][1] = *(const bf16x8*)(vp + 32);
        }

        // S = Q K^T (16q x 64k)
        f32x4 sacc[4];
#pragma unroll
        for (int nt = 0; nt < 4; nt++) {
            sacc[nt] = __builtin_amdgcn_mfma_f32_16x16x32_bf16(qF[0], t.kF[nt][0], zf, 0, 0, 0);
            sacc[nt] = __builtin_amdgcn_mfma_f32_16x16x32_bf16(qF[1], t.kF[nt][1], sacc[nt], 0, 0, 0);
        }

        // p = exp(S*scale); l += p; P' = p*mask*diag -> wave-private LDS strip
#pragma unroll
        for (int cf = 0; cf < 4; cf++) {
#pragma unroll
            for (int r = 0; r < 4; r++) {
                const float p = __builtin_amdgcn_exp2f(sacc[cf][r] * SCALE_LOG2E);
                lacc[r] += p;
                lPw[(quad * 4 + r) * VSTR + cf * 16 + l15] =
                    f2bf(p * t.mv[cf][r] * t.dg[cf]);
            }
        }

        // O += P' @ V  (aP read is wave-private: no barrier, lgkm dep only)
#pragma unroll
        for (int ks = 0; ks < 2; ks++) {
            const bf16x8 aP = *(const bf16x8*)&lPw[l15 * VSTR + ks * 32 + quad * 8];
#pragma unroll
            for (int nt = 0; nt < 4; nt++)
                oacc[nt] = __builtin_amdgcn_mfma_f32_16x16x32_bf16(aP, vF[nt][ks], oacc[nt], 0, 0, 0);
        }
    };

    TileRegs tA, tB;
    load_tile(tA, 0);
    for (int kt = 0; kt < NSEQ; kt += 128) {
        load_tile(tB, kt + 64);           // prefetch while computing A
        compute_tile(tA, kt);
        const int ktn = (kt + 128 < NSEQ) ? (kt + 128) : (NSEQ - 64);  // clamp: last prefetch unused
        load_tile(tA, ktn);
        compute_tile(tB, kt + 64);
    }

    // reduce l across the 16 lanes sharing each q-row
#pragma unroll
    for (int r = 0; r < 4; r++) {
        float v = lacc[r];
        v += __shfl_xor(v, 1);
        v += __shfl_xor(v, 2);
        v += __shfl_xor(v, 4);
        v += __shfl_xor(v, 8);
        lacc[r] = v;
    }

    const int b = bh >> 3, h = bh & 7;
#pragma unroll
    for (int nt = 0; nt < 4; nt++)
#pragma unroll
        for (int r = 0; r < 4; r++) {
            const int qrow = q0 + quad * 4 + r;
            out[((size_t)b * NSEQ + qrow) * D_MODEL + h * HEAD_DIM + nt * 16 + l15] =
                oacc[nt][r] / lacc[r];
        }
}

// ---------------------------------------------------------------------------
extern "C" void kernel_launch(void* const* d_in, const int* in_sizes, int n_in,
                              void* d_out, int out_size, void* d_ws, size_t ws_size,
                              hipStream_t stream) {
    const float* q       = (const float*)d_in[0];
    const float* k       = (const float*)d_in[1];
    const float* v       = (const float*)d_in[2];
    const float* mask    = (const float*)d_in[3];
    const float* pearson = (const float*)d_in[4];
    const float* Wq      = (const float*)d_in[5];
    const float* bq      = (const float*)d_in[6];
    const float* Wk      = (const float*)d_in[7];
    const float* bk      = (const float*)d_in[8];
    const float* Wv      = (const float*)d_in[9];
    const float* bv      = (const float*)d_in[10];

    // ws layout: Qp (4 MB) | Kp (4 MB) | Vt (4 MB, transposed) | diag (128 KB)
    unsigned short* Qp = (unsigned short*)d_ws;
    unsigned short* Kp = Qp + 2097152;
    unsigned short* Vt = Kp + 2097152;
    float* diag = (float*)((char*)d_ws + 12582912);
    float* out = (float*)d_out;

    proj_kernel<<<dim3(32, 8, 3), 256, 0, stream>>>(q, k, v, Wq, Wk, Wv,
                                                    bq, bk, bv, Qp, Kp, Vt);
    diag_kernel<<<dim3(128), 256, 0, stream>>>(pearson, diag);
    attn_kernel<<<dim3(32, 16), 256, 0, stream>>>(Qp, Kp, Vt, diag, mask, out);
}